// Round 18
// baseline (97.431 us; speedup 1.0000x reference)
//
#include <hip/hip_runtime.h>
#include <math.h>

#define NSEQ 4096
#define QSCL (0.17677669529663687f * 1.4426950408889634f)  // 32^-0.5 * log2(e)

typedef __attribute__((ext_vector_type(2))) _Float16 half2v;
typedef __attribute__((ext_vector_type(8))) _Float16 half8;
typedef __attribute__((ext_vector_type(4))) float f32x4;
typedef __attribute__((ext_vector_type(16))) float f32x16;
typedef __attribute__((ext_vector_type(2))) float f32x2;
typedef __attribute__((ext_vector_type(2))) unsigned int u32x2;
typedef __attribute__((ext_vector_type(4))) unsigned int u32x4;

#if __has_builtin(__builtin_amdgcn_exp2f)
#define EXP2(x) __builtin_amdgcn_exp2f(x)
#else
#define EXP2(x) exp2f(x)
#endif

__device__ __forceinline__ half2v pk2(float a, float b) {
  return __builtin_bit_cast(half2v, __builtin_amdgcn_cvt_pkrtz(a, b));
}
__device__ __forceinline__ unsigned pk2u(float a, float b) {
  return __builtin_bit_cast(unsigned, __builtin_amdgcn_cvt_pkrtz(a, b));
}
__device__ __forceinline__ unsigned pkrn(float a, float b) {
  half2v r;
  r[0] = (_Float16)a;
  r[1] = (_Float16)b;
  return __builtin_bit_cast(unsigned, r);
}
__device__ __forceinline__ half8 cvt8rn(float4 a, float4 b) {
  half8 r;
  r[0] = (_Float16)a.x; r[1] = (_Float16)a.y;
  r[2] = (_Float16)a.z; r[3] = (_Float16)a.w;
  r[4] = (_Float16)b.x; r[5] = (_Float16)b.y;
  r[6] = (_Float16)b.z; r[7] = (_Float16)b.w;
  return r;
}

// Quadrant swap between lane halves (verified end-to-end in R9/R11).
__device__ __forceinline__ void swap32(unsigned a, unsigned b, unsigned& r0,
                                       unsigned& r1, int lane) {
#if __has_builtin(__builtin_amdgcn_permlane32_swap)
  typedef __attribute__((ext_vector_type(2))) unsigned uint2v;
  uint2v s = __builtin_amdgcn_permlane32_swap(a, b, false, false);
  r0 = s[0];
  r1 = s[1];
#else
  unsigned ax = __shfl_xor((int)a, 32), bx = __shfl_xor((int)b, 32);
  const bool lo = lane < 32;
  r0 = lo ? a : bx;
  r1 = lo ? ax : b;
#endif
}

// ---------------------------------------------------------------------------
// Fused QKV GEMM (R16-proven): x fp32 staged to LDS fp16 (packed pair
// writes), qkv_w fp32 converted RTN in-register, single-term fp16 MFMA.
// Q -> Qp [bh][n][32]*QSCL, K -> Kp [bh][n][32], V -> Vp [bh][32][n].
// grid (64, 6, 2), block 256 (4 waves, each 32m x 64n).
// ---------------------------------------------------------------------------
__global__ __launch_bounds__(256) void gemm_qkv(
    const float* __restrict__ Wf, const float* __restrict__ x,
    const float* __restrict__ bias, _Float16* __restrict__ Qp,
    _Float16* __restrict__ Kp, _Float16* __restrict__ Vp) {
  __shared__ _Float16 XT[64][72];  // [n][ch-in-chunk], 144B rows (16B-align)
  const int b = blockIdx.z, n0 = blockIdx.x * 64, m0 = blockIdx.y * 128;
  const int tid = threadIdx.x, w = tid >> 6, lane = tid & 63;
  const int lq = lane & 15, g = lane >> 4;
  const int mw = m0 + w * 32;
  const int cp = tid >> 4, nn = (tid & 15) * 4;
  f32x4 acc[2][4] = {};
  const size_t wr0 = (size_t)(mw + lq) * 256 + 8 * g;
  const size_t wr1 = (size_t)(mw + 16 + lq) * 256 + 8 * g;

  for (int kc = 0; kc < 4; ++kc) {
    if (kc) __syncthreads();
    #pragma unroll
    for (int i = 0; i < 2; ++i) {
      const int cb = (cp + 16 * i) * 2;  // even channel within chunk, 0..62
      const float* xs = x + ((size_t)(b * 256 + kc * 64 + cb)) * NSEQ + n0 + nn;
      float4 va = *(const float4*)(xs);
      float4 vb = *(const float4*)(xs + NSEQ);
      *(unsigned*)&XT[nn + 0][cb] = pkrn(va.x, vb.x);
      *(unsigned*)&XT[nn + 1][cb] = pkrn(va.y, vb.y);
      *(unsigned*)&XT[nn + 2][cb] = pkrn(va.z, vb.z);
      *(unsigned*)&XT[nn + 3][cb] = pkrn(va.w, vb.w);
    }
    __syncthreads();
    #pragma unroll
    for (int kh = 0; kh < 2; ++kh) {
      const int k0 = kc * 64 + kh * 32;
      float4 wa0 = *(const float4*)(Wf + wr0 + k0);
      float4 wa1 = *(const float4*)(Wf + wr0 + k0 + 4);
      float4 wb0 = *(const float4*)(Wf + wr1 + k0);
      float4 wb1 = *(const float4*)(Wf + wr1 + k0 + 4);
      half8 ah0 = cvt8rn(wa0, wa1);
      half8 ah1 = cvt8rn(wb0, wb1);
      const int dk = kh * 32 + 8 * g;
      #pragma unroll
      for (int ns = 0; ns < 4; ++ns) {
        half8 bh_ = *(const half8*)&XT[ns * 16 + lq][dk];
        acc[0][ns] = __builtin_amdgcn_mfma_f32_16x16x32_f16(ah0, bh_, acc[0][ns], 0, 0, 0);
        acc[1][ns] = __builtin_amdgcn_mfma_f32_16x16x32_f16(ah1, bh_, acc[1][ns], 0, 0, 0);
      }
    }
  }
  const int seg = mw >> 8;  // 0=Q, 1=K, 2=V
  const int hh = (mw >> 5) & 7;
  const int bhi = b * 8 + hh;
  #pragma unroll
  for (int ms = 0; ms < 2; ++ms) {
    const int dbase = ms * 16 + 4 * g;
    float4 bi = *(const float4*)(bias + mw + dbase);
    #pragma unroll
    for (int ns = 0; ns < 4; ++ns) {
      const int n = n0 + ns * 16 + lq;
      float v0 = acc[ms][ns][0] + bi.x;
      float v1 = acc[ms][ns][1] + bi.y;
      float v2 = acc[ms][ns][2] + bi.z;
      float v3 = acc[ms][ns][3] + bi.w;
      if (seg == 0) {
        v0 *= QSCL; v1 *= QSCL; v2 *= QSCL; v3 *= QSCL;
        u32x2 H;
        H[0] = pk2u(v0, v1);
        H[1] = pk2u(v2, v3);
        *(u32x2*)(Qp + ((size_t)bhi * NSEQ + n) * 32 + dbase) = H;
      } else if (seg == 1) {
        u32x2 H;
        H[0] = pk2u(v0, v1);
        H[1] = pk2u(v2, v3);
        *(u32x2*)(Kp + ((size_t)bhi * NSEQ + n) * 32 + dbase) = H;
      } else {
        Vp[((size_t)bhi * 32 + dbase + 0) * NSEQ + n] = (_Float16)v0;
        Vp[((size_t)bhi * 32 + dbase + 1) * NSEQ + n] = (_Float16)v1;
        Vp[((size_t)bhi * 32 + dbase + 2) * NSEQ + n] = (_Float16)v2;
        Vp[((size_t)bhi * 32 + dbase + 3) * NSEQ + n] = (_Float16)v3;
      }
    }
  }
}

// ---------------------------------------------------------------------------
// Flash attention partial: R16 body, KEY-SPLIT 4 (1024 keys/slice) for TLP.
// __launch_bounds__(256,2) kept so the compiler retains the ~104-VGPR
// allocation (R12's regression = bounds(256,4) shrank it to 64 + spills);
// at 104 VGPR the HW still fits 4 blocks/CU with 1024 blocks.
// grid (64, 8, 2): bx = qt(16) | ks(4)<<4. block 256 (4 waves).
// pp[(bh*4+ks)][q][32] normalized fp16 partial; lsum[bh][q][4] f32.
// ---------------------------------------------------------------------------
__global__ __launch_bounds__(256, 2) void attn_part(
    const _Float16* __restrict__ Qp, const _Float16* __restrict__ Kp,
    const _Float16* __restrict__ Vp, _Float16* __restrict__ pp,
    float* __restrict__ lsum) {
  const int b = blockIdx.z, h = blockIdx.y, bh = b * 8 + h;
  const int qt = blockIdx.x & 15, ks_ = blockIdx.x >> 4;
  const int tid = threadIdx.x, w = tid >> 6, lane = tid & 63;
  const int l31 = lane & 31, hw = lane >> 5;
  const int hi8 = hw * 8;
  const int n0 = qt * 256 + w * 64;  // wave's q base: 2 streams of 32

  half8 qf[2][2];
  #pragma unroll
  for (int s = 0; s < 2; ++s)
    #pragma unroll
    for (int dh = 0; dh < 2; ++dh)
      qf[s][dh] = *(const half8*)(Qp + ((size_t)bh * NSEQ + n0 + s * 32 + l31) * 32 +
                                  dh * 16 + hi8);

  f32x16 acc[2] = {};
  float lp[2][4] = {};
  const _Float16* Kb = Kp + ((size_t)bh * NSEQ + ks_ * 1024) * 32;
  const _Float16* Vb = Vp + (size_t)bh * 32 * NSEQ + ks_ * 1024;

  half8 kA[4], kB[4];

  auto kload = [&](half8* dst, int t) {
    const int key0 = t * 64;
    #pragma unroll
    for (int kt = 0; kt < 2; ++kt)
      #pragma unroll
      for (int dh = 0; dh < 2; ++dh)
        dst[kt * 2 + dh] = *(const half8*)(Kb + (size_t)(key0 + kt * 32 + l31) * 32 +
                                           dh * 16 + hi8);
  };

  auto compute = [&](const half8* kf, int t) {
    const int key0 = t * 64;
    half8 vf[4];
    #pragma unroll
    for (int c = 0; c < 4; ++c)
      vf[c] = *(const half8*)(Vb + (size_t)l31 * NSEQ + key0 + c * 16 + hi8);
    __builtin_amdgcn_s_setprio(1);
    #pragma unroll
    for (int s = 0; s < 2; ++s) {
      #pragma unroll
      for (int kt = 0; kt < 2; ++kt) {
        f32x16 sc = {0.f, 0.f, 0.f, 0.f, 0.f, 0.f, 0.f, 0.f,
                     0.f, 0.f, 0.f, 0.f, 0.f, 0.f, 0.f, 0.f};
        sc = __builtin_amdgcn_mfma_f32_32x32x16_f16(kf[kt * 2 + 0], qf[s][0], sc, 0, 0, 0);
        sc = __builtin_amdgcn_mfma_f32_32x32x16_f16(kf[kt * 2 + 1], qf[s][1], sc, 0, 0, 0);
        float p[16];
        #pragma unroll
        for (int i = 0; i < 16; ++i) {
          p[i] = EXP2(sc[i]);
          lp[s][i & 3] += p[i];
        }
        #pragma unroll
        for (int cc = 0; cc < 2; ++cc) {
          unsigned A01 = pk2u(p[cc * 8 + 0], p[cc * 8 + 1]);
          unsigned A23 = pk2u(p[cc * 8 + 2], p[cc * 8 + 3]);
          unsigned A45 = pk2u(p[cc * 8 + 4], p[cc * 8 + 5]);
          unsigned A67 = pk2u(p[cc * 8 + 6], p[cc * 8 + 7]);
          unsigned r0, r1, r2, r3;
          swap32(A01, A45, r0, r1, lane);
          swap32(A23, A67, r2, r3, lane);
          u32x4 W;
          W[0] = r0;
          W[1] = r2;
          W[2] = r1;
          W[3] = r3;
          half8 pb = __builtin_bit_cast(half8, W);
          acc[s] = __builtin_amdgcn_mfma_f32_32x32x16_f16(vf[kt * 2 + cc], pb, acc[s], 0, 0, 0);
        }
      }
    }
    __builtin_amdgcn_s_setprio(0);
  };

  kload(kA, 0);
  #pragma unroll 1
  for (int t = 0; t < 16; t += 2) {
    kload(kB, t + 1);
    compute(kA, t);
    kload(kA, t + 2 < 16 ? t + 2 : 15);
    compute(kB, t + 1);
  }

  // ---- per-stream l reduction; normalized fp16 partial + l ----
  #pragma unroll
  for (int s = 0; s < 2; ++s) {
    float l = (lp[s][0] + lp[s][1]) + (lp[s][2] + lp[s][3]);
    l += __shfl_xor(l, 32);
    const float inv = 1.f / l;
    const int q = n0 + s * 32 + l31;
    const size_t pbase = ((size_t)(bh * 4 + ks_) * NSEQ + q) * 32;
    #pragma unroll
    for (int rg = 0; rg < 4; ++rg) {
      const int d0 = rg * 8 + 4 * hw;
      float v0 = acc[s][rg * 4 + 0] * inv, v1 = acc[s][rg * 4 + 1] * inv;
      float v2 = acc[s][rg * 4 + 2] * inv, v3 = acc[s][rg * 4 + 3] * inv;
      u32x2 H;
      H[0] = pk2u(v0, v1);
      H[1] = pk2u(v2, v3);
      *(u32x2*)(pp + pbase + d0) = H;
    }
    if (lane < 32) lsum[((size_t)bh * NSEQ + q) * 4 + ks_] = l;
  }
}

// ---------------------------------------------------------------------------
// Output projection: out_w fp32 split hi/lo in-register (2-term MFMA) +
// INLINE 4-way key-split combine in packed fp16. grid (64, 4, 2), block 256.
// ---------------------------------------------------------------------------
__global__ __launch_bounds__(256) void gemm_proj(
    const float* __restrict__ Wf, const _Float16* __restrict__ pp,
    const float* __restrict__ lsum, const float* __restrict__ bias,
    float* __restrict__ out) {
  const int b = blockIdx.z, n0 = blockIdx.x * 64, m0 = blockIdx.y * 64;
  const int tid = threadIdx.x, w = tid >> 6, lane = tid & 63;
  const int lq = lane & 15, g = lane >> 4;
  const int mw = m0 + w * 16;
  f32x4 acc[4] = {};
  const size_t wr = (size_t)(mw + lq) * 256 + 8 * g;
  #pragma unroll
  for (int k0 = 0; k0 < 256; k0 += 32) {
    // W hi/lo split (compensated 2-term)
    float4 wa0 = *(const float4*)(Wf + wr + k0);
    float4 wa1 = *(const float4*)(Wf + wr + k0 + 4);
    half2v h0 = pk2(wa0.x, wa0.y), h1 = pk2(wa0.z, wa0.w);
    half2v h2 = pk2(wa1.x, wa1.y), h3 = pk2(wa1.z, wa1.w);
    half8 ah, al;
    ah[0] = h0[0]; ah[1] = h0[1]; ah[2] = h1[0]; ah[3] = h1[1];
    ah[4] = h2[0]; ah[5] = h2[1]; ah[6] = h3[0]; ah[7] = h3[1];
    half2v e0 = pk2(wa0.x - (float)h0[0], wa0.y - (float)h0[1]);
    half2v e1 = pk2(wa0.z - (float)h1[0], wa0.w - (float)h1[1]);
    half2v e2 = pk2(wa1.x - (float)h2[0], wa1.y - (float)h2[1]);
    half2v e3 = pk2(wa1.z - (float)h3[0], wa1.w - (float)h3[1]);
    al[0] = e0[0]; al[1] = e0[1]; al[2] = e1[0]; al[3] = e1[1];
    al[4] = e2[0]; al[5] = e2[1]; al[6] = e3[0]; al[7] = e3[1];
    const int c = k0 + 8 * g;  // channel of this 8-elem chunk
    const int hch = c >> 5, d0 = c & 31;
    const int bh = b * 8 + hch;
    #pragma unroll
    for (int ns = 0; ns < 4; ++ns) {
      const int n = n0 + ns * 16 + lq;
      const size_t pb = ((size_t)(bh * 4) * NSEQ + n) * 32 + d0;
      half8 p0 = *(const half8*)(pp + pb);
      half8 p1 = *(const half8*)(pp + pb + (size_t)NSEQ * 32);
      half8 p2 = *(const half8*)(pp + pb + (size_t)NSEQ * 64);
      half8 p3 = *(const half8*)(pp + pb + (size_t)NSEQ * 96);
      f32x4 lv = *(const f32x4*)(lsum + ((size_t)bh * NSEQ + n) * 4);
      const float iv = 1.f / (lv[0] + lv[1] + lv[2] + lv[3]);
      const _Float16 w0h = (_Float16)(lv[0] * iv);
      const _Float16 w1h = (_Float16)(lv[1] * iv);
      const _Float16 w2h = (_Float16)(lv[2] * iv);
      const _Float16 w3h = (_Float16)(lv[3] * iv);
      half8 bh_ = p0 * w0h + p1 * w1h + p2 * w2h + p3 * w3h;  // packed fp16
      acc[ns] = __builtin_amdgcn_mfma_f32_16x16x32_f16(ah, bh_, acc[ns], 0, 0, 0);
      acc[ns] = __builtin_amdgcn_mfma_f32_16x16x32_f16(al, bh_, acc[ns], 0, 0, 0);
    }
  }
  float4 bi = *(const float4*)(bias + mw + 4 * g);
  #pragma unroll
  for (int ns = 0; ns < 4; ++ns) {
    const int n = n0 + ns * 16 + lq;
    out[((size_t)b * 256 + mw + 4 * g + 0) * NSEQ + n] = acc[ns][0] + bi.x;
    out[((size_t)b * 256 + mw + 4 * g + 1) * NSEQ + n] = acc[ns][1] + bi.y;
    out[((size_t)b * 256 + mw + 4 * g + 2) * NSEQ + n] = acc[ns][2] + bi.z;
    out[((size_t)b * 256 + mw + 4 * g + 3) * NSEQ + n] = acc[ns][3] + bi.w;
  }
}

// ---------------------------------------------------------------------------
extern "C" void kernel_launch(void* const* d_in, const int* in_sizes, int n_in,
                              void* d_out, int out_size, void* d_ws, size_t ws_size,
                              hipStream_t stream) {
  const float* x = (const float*)d_in[0];
  const float* qkv_w = (const float*)d_in[1];
  const float* qkv_b = (const float*)d_in[2];
  const float* out_w = (const float*)d_in[3];
  const float* out_b = (const float*)d_in[4];
  float* out = (float*)d_out;

  char* ws = (char*)d_ws;
  _Float16* Vp = (_Float16*)(ws);                // [16][32][4096] 4MB
  _Float16* Qp = (_Float16*)(ws + (4u << 20));   // [16][4096][32] 4MB
  _Float16* Kp = (_Float16*)(ws + (8u << 20));   // 4MB
  _Float16* pp = (_Float16*)(ws + (12u << 20));  // [64 planes] 16MB
  float* lsum = (float*)(ws + (28u << 20));      // [16][4096][4] f32 1MB

  gemm_qkv<<<dim3(NSEQ / 64, 6, 2), 256, 0, stream>>>(qkv_w, x, qkv_b,
                                                      Qp, Kp, Vp);
  attn_part<<<dim3(64, 8, 2), 256, 0, stream>>>(Qp, Kp, Vp, pp, lsum);
  gemm_proj<<<dim3(NSEQ / 64, 4, 2), 256, 0, stream>>>(out_w, pp, lsum,
                                                       out_b, out);
}

// Round 19
// 87.766 us; speedup vs baseline: 1.1101x; 1.1101x over previous
//
#include <hip/hip_runtime.h>
#include <math.h>

#define NSEQ 4096
#define QSCL (0.17677669529663687f * 1.4426950408889634f)  // 32^-0.5 * log2(e)

typedef __attribute__((ext_vector_type(2))) _Float16 half2v;
typedef __attribute__((ext_vector_type(2))) __fp16 fp16x2;
typedef __attribute__((ext_vector_type(8))) _Float16 half8;
typedef __attribute__((ext_vector_type(4))) float f32x4;
typedef __attribute__((ext_vector_type(16))) float f32x16;
typedef __attribute__((ext_vector_type(2))) float f32x2;
typedef __attribute__((ext_vector_type(2))) unsigned int u32x2;
typedef __attribute__((ext_vector_type(4))) unsigned int u32x4;

#if __has_builtin(__builtin_amdgcn_exp2f)
#define EXP2(x) __builtin_amdgcn_exp2f(x)
#else
#define EXP2(x) exp2f(x)
#endif

__device__ __forceinline__ half2v pk2(float a, float b) {
  return __builtin_bit_cast(half2v, __builtin_amdgcn_cvt_pkrtz(a, b));
}
__device__ __forceinline__ unsigned pk2u(float a, float b) {
  return __builtin_bit_cast(unsigned, __builtin_amdgcn_cvt_pkrtz(a, b));
}
__device__ __forceinline__ unsigned pkrn(float a, float b) {
  half2v r;
  r[0] = (_Float16)a;
  r[1] = (_Float16)b;
  return __builtin_bit_cast(unsigned, r);
}
__device__ __forceinline__ half8 cvt8rn(float4 a, float4 b) {
  half8 r;
  r[0] = (_Float16)a.x; r[1] = (_Float16)a.y;
  r[2] = (_Float16)a.z; r[3] = (_Float16)a.w;
  r[4] = (_Float16)b.x; r[5] = (_Float16)b.y;
  r[6] = (_Float16)b.z; r[7] = (_Float16)b.w;
  return r;
}
// c += pair.lo + pair.hi in one VALU op (v_dot2_f32_f16 with B=(1,1)).
__device__ __forceinline__ float fdot2acc(unsigned a, float c) {
#if __has_builtin(__builtin_amdgcn_fdot2)
  fp16x2 one = {(__fp16)1.0f, (__fp16)1.0f};
  return __builtin_amdgcn_fdot2(__builtin_bit_cast(fp16x2, a), one, c, false);
#else
  half2v v = __builtin_bit_cast(half2v, a);
  return c + (float)v[0] + (float)v[1];
#endif
}

// Quadrant swap between lane halves (verified end-to-end in R9/R11).
__device__ __forceinline__ void swap32(unsigned a, unsigned b, unsigned& r0,
                                       unsigned& r1, int lane) {
#if __has_builtin(__builtin_amdgcn_permlane32_swap)
  typedef __attribute__((ext_vector_type(2))) unsigned uint2v;
  uint2v s = __builtin_amdgcn_permlane32_swap(a, b, false, false);
  r0 = s[0];
  r1 = s[1];
#else
  unsigned ax = __shfl_xor((int)a, 32), bx = __shfl_xor((int)b, 32);
  const bool lo = lane < 32;
  r0 = lo ? a : bx;
  r1 = lo ? ax : b;
#endif
}

// ---------------------------------------------------------------------------
// Fused QKV GEMM (R16-proven, unchanged): x fp32 staged to LDS fp16 (packed
// pair writes), qkv_w fp32 converted RTN in-register, single-term fp16 MFMA.
// Q -> Qp [bh][n][32]*QSCL, K -> Kp [bh][n][32], V -> Vp [bh][32][n].
// grid (64, 6, 2), block 256 (4 waves, each 32m x 64n).
// ---------------------------------------------------------------------------
__global__ __launch_bounds__(256) void gemm_qkv(
    const float* __restrict__ Wf, const float* __restrict__ x,
    const float* __restrict__ bias, _Float16* __restrict__ Qp,
    _Float16* __restrict__ Kp, _Float16* __restrict__ Vp) {
  __shared__ _Float16 XT[64][72];  // [n][ch-in-chunk], 144B rows (16B-align)
  const int b = blockIdx.z, n0 = blockIdx.x * 64, m0 = blockIdx.y * 128;
  const int tid = threadIdx.x, w = tid >> 6, lane = tid & 63;
  const int lq = lane & 15, g = lane >> 4;
  const int mw = m0 + w * 32;
  const int cp = tid >> 4, nn = (tid & 15) * 4;
  f32x4 acc[2][4] = {};
  const size_t wr0 = (size_t)(mw + lq) * 256 + 8 * g;
  const size_t wr1 = (size_t)(mw + 16 + lq) * 256 + 8 * g;

  for (int kc = 0; kc < 4; ++kc) {
    if (kc) __syncthreads();
    #pragma unroll
    for (int i = 0; i < 2; ++i) {
      const int cb = (cp + 16 * i) * 2;  // even channel within chunk, 0..62
      const float* xs = x + ((size_t)(b * 256 + kc * 64 + cb)) * NSEQ + n0 + nn;
      float4 va = *(const float4*)(xs);
      float4 vb = *(const float4*)(xs + NSEQ);
      *(unsigned*)&XT[nn + 0][cb] = pkrn(va.x, vb.x);
      *(unsigned*)&XT[nn + 1][cb] = pkrn(va.y, vb.y);
      *(unsigned*)&XT[nn + 2][cb] = pkrn(va.z, vb.z);
      *(unsigned*)&XT[nn + 3][cb] = pkrn(va.w, vb.w);
    }
    __syncthreads();
    #pragma unroll
    for (int kh = 0; kh < 2; ++kh) {
      const int k0 = kc * 64 + kh * 32;
      float4 wa0 = *(const float4*)(Wf + wr0 + k0);
      float4 wa1 = *(const float4*)(Wf + wr0 + k0 + 4);
      float4 wb0 = *(const float4*)(Wf + wr1 + k0);
      float4 wb1 = *(const float4*)(Wf + wr1 + k0 + 4);
      half8 ah0 = cvt8rn(wa0, wa1);
      half8 ah1 = cvt8rn(wb0, wb1);
      const int dk = kh * 32 + 8 * g;
      #pragma unroll
      for (int ns = 0; ns < 4; ++ns) {
        half8 bh_ = *(const half8*)&XT[ns * 16 + lq][dk];
        acc[0][ns] = __builtin_amdgcn_mfma_f32_16x16x32_f16(ah0, bh_, acc[0][ns], 0, 0, 0);
        acc[1][ns] = __builtin_amdgcn_mfma_f32_16x16x32_f16(ah1, bh_, acc[1][ns], 0, 0, 0);
      }
    }
  }
  const int seg = mw >> 8;  // 0=Q, 1=K, 2=V
  const int hh = (mw >> 5) & 7;
  const int bhi = b * 8 + hh;
  #pragma unroll
  for (int ms = 0; ms < 2; ++ms) {
    const int dbase = ms * 16 + 4 * g;
    float4 bi = *(const float4*)(bias + mw + dbase);
    #pragma unroll
    for (int ns = 0; ns < 4; ++ns) {
      const int n = n0 + ns * 16 + lq;
      float v0 = acc[ms][ns][0] + bi.x;
      float v1 = acc[ms][ns][1] + bi.y;
      float v2 = acc[ms][ns][2] + bi.z;
      float v3 = acc[ms][ns][3] + bi.w;
      if (seg == 0) {
        v0 *= QSCL; v1 *= QSCL; v2 *= QSCL; v3 *= QSCL;
        u32x2 H;
        H[0] = pk2u(v0, v1);
        H[1] = pk2u(v2, v3);
        *(u32x2*)(Qp + ((size_t)bhi * NSEQ + n) * 32 + dbase) = H;
      } else if (seg == 1) {
        u32x2 H;
        H[0] = pk2u(v0, v1);
        H[1] = pk2u(v2, v3);
        *(u32x2*)(Kp + ((size_t)bhi * NSEQ + n) * 32 + dbase) = H;
      } else {
        Vp[((size_t)bhi * 32 + dbase + 0) * NSEQ + n] = (_Float16)v0;
        Vp[((size_t)bhi * 32 + dbase + 1) * NSEQ + n] = (_Float16)v1;
        Vp[((size_t)bhi * 32 + dbase + 2) * NSEQ + n] = (_Float16)v2;
        Vp[((size_t)bhi * 32 + dbase + 3) * NSEQ + n] = (_Float16)v3;
      }
    }
  }
}

// ---------------------------------------------------------------------------
// Flash attention partial: R16 body + fdot2 l-accumulation from the packed
// P pairs (replaces 16 scalar f32 adds per kt-stream with 4 v_dot2_f32_f16).
// 32x32x16 MFMA, permlane P redistribution (no LDS), fixed-max softmax,
// key-split 2, depth-1 K prefetch, early V issue, 2 independent 32-q
// streams/wave, setprio around hot section.
// grid (32, 8, 2): bx = qt(16) | ks(2)<<4. block 256 (4 waves).
// pp[(bh*2+ks)][q][32] normalized fp16 partial; lsum[bh][q][2] f32.
// ---------------------------------------------------------------------------
__global__ __launch_bounds__(256, 2) void attn_part(
    const _Float16* __restrict__ Qp, const _Float16* __restrict__ Kp,
    const _Float16* __restrict__ Vp, _Float16* __restrict__ pp,
    float* __restrict__ lsum) {
  const int b = blockIdx.z, h = blockIdx.y, bh = b * 8 + h;
  const int qt = blockIdx.x & 15, ks_ = blockIdx.x >> 4;
  const int tid = threadIdx.x, w = tid >> 6, lane = tid & 63;
  const int l31 = lane & 31, hw = lane >> 5;
  const int hi8 = hw * 8;
  const int n0 = qt * 256 + w * 64;  // wave's q base: 2 streams of 32

  half8 qf[2][2];
  #pragma unroll
  for (int s = 0; s < 2; ++s)
    #pragma unroll
    for (int dh = 0; dh < 2; ++dh)
      qf[s][dh] = *(const half8*)(Qp + ((size_t)bh * NSEQ + n0 + s * 32 + l31) * 32 +
                                  dh * 16 + hi8);

  f32x16 acc[2] = {};
  float lp[2][4] = {};
  const _Float16* Kb = Kp + ((size_t)bh * NSEQ + ks_ * 2048) * 32;
  const _Float16* Vb = Vp + (size_t)bh * 32 * NSEQ + ks_ * 2048;

  half8 kA[4], kB[4];

  auto kload = [&](half8* dst, int t) {
    const int key0 = t * 64;
    #pragma unroll
    for (int kt = 0; kt < 2; ++kt)
      #pragma unroll
      for (int dh = 0; dh < 2; ++dh)
        dst[kt * 2 + dh] = *(const half8*)(Kb + (size_t)(key0 + kt * 32 + l31) * 32 +
                                           dh * 16 + hi8);
  };

  auto compute = [&](const half8* kf, int t) {
    const int key0 = t * 64;
    half8 vf[4];
    #pragma unroll
    for (int c = 0; c < 4; ++c)
      vf[c] = *(const half8*)(Vb + (size_t)l31 * NSEQ + key0 + c * 16 + hi8);
    __builtin_amdgcn_s_setprio(1);
    #pragma unroll
    for (int s = 0; s < 2; ++s) {
      #pragma unroll
      for (int kt = 0; kt < 2; ++kt) {
        f32x16 sc = {0.f, 0.f, 0.f, 0.f, 0.f, 0.f, 0.f, 0.f,
                     0.f, 0.f, 0.f, 0.f, 0.f, 0.f, 0.f, 0.f};
        sc = __builtin_amdgcn_mfma_f32_32x32x16_f16(kf[kt * 2 + 0], qf[s][0], sc, 0, 0, 0);
        sc = __builtin_amdgcn_mfma_f32_32x32x16_f16(kf[kt * 2 + 1], qf[s][1], sc, 0, 0, 0);
        float p[16];
        #pragma unroll
        for (int i = 0; i < 16; ++i) p[i] = EXP2(sc[i]);
        #pragma unroll
        for (int cc = 0; cc < 2; ++cc) {
          unsigned A01 = pk2u(p[cc * 8 + 0], p[cc * 8 + 1]);
          unsigned A23 = pk2u(p[cc * 8 + 2], p[cc * 8 + 3]);
          unsigned A45 = pk2u(p[cc * 8 + 4], p[cc * 8 + 5]);
          unsigned A67 = pk2u(p[cc * 8 + 6], p[cc * 8 + 7]);
          lp[s][0] = fdot2acc(A01, lp[s][0]);
          lp[s][1] = fdot2acc(A23, lp[s][1]);
          lp[s][2] = fdot2acc(A45, lp[s][2]);
          lp[s][3] = fdot2acc(A67, lp[s][3]);
          unsigned r0, r1, r2, r3;
          swap32(A01, A45, r0, r1, lane);
          swap32(A23, A67, r2, r3, lane);
          u32x4 W;
          W[0] = r0;
          W[1] = r2;
          W[2] = r1;
          W[3] = r3;
          half8 pb = __builtin_bit_cast(half8, W);
          acc[s] = __builtin_amdgcn_mfma_f32_32x32x16_f16(vf[kt * 2 + cc], pb, acc[s], 0, 0, 0);
        }
      }
    }
    __builtin_amdgcn_s_setprio(0);
  };

  kload(kA, 0);
  #pragma unroll 1
  for (int t = 0; t < 32; t += 2) {
    kload(kB, t + 1);
    compute(kA, t);
    kload(kA, t + 2 < 32 ? t + 2 : 31);
    compute(kB, t + 1);
  }

  // ---- per-stream l reduction; normalized fp16 partial + l ----
  #pragma unroll
  for (int s = 0; s < 2; ++s) {
    float l = (lp[s][0] + lp[s][1]) + (lp[s][2] + lp[s][3]);
    l += __shfl_xor(l, 32);
    const float inv = 1.f / l;
    const int q = n0 + s * 32 + l31;
    const size_t pbase = ((size_t)(bh * 2 + ks_) * NSEQ + q) * 32;
    #pragma unroll
    for (int rg = 0; rg < 4; ++rg) {
      const int d0 = rg * 8 + 4 * hw;
      float v0 = acc[s][rg * 4 + 0] * inv, v1 = acc[s][rg * 4 + 1] * inv;
      float v2 = acc[s][rg * 4 + 2] * inv, v3 = acc[s][rg * 4 + 3] * inv;
      u32x2 H;
      H[0] = pk2u(v0, v1);
      H[1] = pk2u(v2, v3);
      *(u32x2*)(pp + pbase + d0) = H;
    }
    if (lane < 32) lsum[((size_t)bh * NSEQ + q) * 2 + ks_] = l;
  }
}

// ---------------------------------------------------------------------------
// Output projection (R16-proven, unchanged): out_w fp32 split hi/lo
// in-register (2-term MFMA) + INLINE key-split combine in packed fp16.
// grid (64, 4, 2), block 256.
// ---------------------------------------------------------------------------
__global__ __launch_bounds__(256) void gemm_proj(
    const float* __restrict__ Wf, const _Float16* __restrict__ pp,
    const float* __restrict__ lsum, const float* __restrict__ bias,
    float* __restrict__ out) {
  const int b = blockIdx.z, n0 = blockIdx.x * 64, m0 = blockIdx.y * 64;
  const int tid = threadIdx.x, w = tid >> 6, lane = tid & 63;
  const int lq = lane & 15, g = lane >> 4;
  const int mw = m0 + w * 16;
  f32x4 acc[4] = {};
  const size_t wr = (size_t)(mw + lq) * 256 + 8 * g;
  #pragma unroll
  for (int k0 = 0; k0 < 256; k0 += 32) {
    float4 wa0 = *(const float4*)(Wf + wr + k0);
    float4 wa1 = *(const float4*)(Wf + wr + k0 + 4);
    half2v h0 = pk2(wa0.x, wa0.y), h1 = pk2(wa0.z, wa0.w);
    half2v h2 = pk2(wa1.x, wa1.y), h3 = pk2(wa1.z, wa1.w);
    half8 ah, al;
    ah[0] = h0[0]; ah[1] = h0[1]; ah[2] = h1[0]; ah[3] = h1[1];
    ah[4] = h2[0]; ah[5] = h2[1]; ah[6] = h3[0]; ah[7] = h3[1];
    half2v e0 = pk2(wa0.x - (float)h0[0], wa0.y - (float)h0[1]);
    half2v e1 = pk2(wa0.z - (float)h1[0], wa0.w - (float)h1[1]);
    half2v e2 = pk2(wa1.x - (float)h2[0], wa1.y - (float)h2[1]);
    half2v e3 = pk2(wa1.z - (float)h3[0], wa1.w - (float)h3[1]);
    al[0] = e0[0]; al[1] = e0[1]; al[2] = e1[0]; al[3] = e1[1];
    al[4] = e2[0]; al[5] = e2[1]; al[6] = e3[0]; al[7] = e3[1];
    const int c = k0 + 8 * g;  // channel of this 8-elem chunk
    const int hch = c >> 5, d0 = c & 31;
    const int bh = b * 8 + hch;
    #pragma unroll
    for (int ns = 0; ns < 4; ++ns) {
      const int n = n0 + ns * 16 + lq;
      const size_t pb = ((size_t)(bh * 2) * NSEQ + n) * 32 + d0;
      half8 pa = *(const half8*)(pp + pb);
      half8 pbp = *(const half8*)(pp + pb + (size_t)NSEQ * 32);
      f32x2 lv = *(const f32x2*)(lsum + ((size_t)bh * NSEQ + n) * 2);
      const float iv = 1.f / (lv[0] + lv[1]);
      const _Float16 w0h = (_Float16)(lv[0] * iv);
      const _Float16 w1h = (_Float16)(lv[1] * iv);
      half8 bh_ = pa * w0h + pbp * w1h;  // packed fp16 mul/fma
      acc[ns] = __builtin_amdgcn_mfma_f32_16x16x32_f16(ah, bh_, acc[ns], 0, 0, 0);
      acc[ns] = __builtin_amdgcn_mfma_f32_16x16x32_f16(al, bh_, acc[ns], 0, 0, 0);
    }
  }
  float4 bi = *(const float4*)(bias + mw + 4 * g);
  #pragma unroll
  for (int ns = 0; ns < 4; ++ns) {
    const int n = n0 + ns * 16 + lq;
    out[((size_t)b * 256 + mw + 4 * g + 0) * NSEQ + n] = acc[ns][0] + bi.x;
    out[((size_t)b * 256 + mw + 4 * g + 1) * NSEQ + n] = acc[ns][1] + bi.y;
    out[((size_t)b * 256 + mw + 4 * g + 2) * NSEQ + n] = acc[ns][2] + bi.z;
    out[((size_t)b * 256 + mw + 4 * g + 3) * NSEQ + n] = acc[ns][3] + bi.w;
  }
}

// ---------------------------------------------------------------------------
extern "C" void kernel_launch(void* const* d_in, const int* in_sizes, int n_in,
                              void* d_out, int out_size, void* d_ws, size_t ws_size,
                              hipStream_t stream) {
  const float* x = (const float*)d_in[0];
  const float* qkv_w = (const float*)d_in[1];
  const float* qkv_b = (const float*)d_in[2];
  const float* out_w = (const float*)d_in[3];
  const float* out_b = (const float*)d_in[4];
  float* out = (float*)d_out;

  char* ws = (char*)d_ws;
  _Float16* Vp = (_Float16*)(ws);                // [16][32][4096] 4MB
  _Float16* Qp = (_Float16*)(ws + (4u << 20));   // [16][4096][32] 4MB
  _Float16* Kp = (_Float16*)(ws + (8u << 20));   // 4MB
  _Float16* pp = (_Float16*)(ws + (12u << 20));  // [32 planes] 8MB
  float* lsum = (float*)(ws + (20u << 20));      // [16][4096][2] f32 512KB

  gemm_qkv<<<dim3(NSEQ / 64, 6, 2), 256, 0, stream>>>(qkv_w, x, qkv_b,
                                                      Qp, Kp, Vp);
  attn_part<<<dim3(32, 8, 2), 256, 0, stream>>>(Qp, Kp, Vp, pp, lsum);
  gemm_proj<<<dim3(NSEQ / 64, 4, 2), 256, 0, stream>>>(out_w, pp, lsum,
                                                       out_b, out);
}

// Round 20
// 87.378 us; speedup vs baseline: 1.1150x; 1.0044x over previous
//
#include <hip/hip_runtime.h>
#include <math.h>

#define NSEQ 4096
#define QSCL (0.17677669529663687f * 1.4426950408889634f)  // 32^-0.5 * log2(e)

typedef __attribute__((ext_vector_type(2))) _Float16 half2v;
typedef __attribute__((ext_vector_type(2))) __fp16 fp16x2;
typedef __attribute__((ext_vector_type(8))) _Float16 half8;
typedef __attribute__((ext_vector_type(4))) float f32x4;
typedef __attribute__((ext_vector_type(16))) float f32x16;
typedef __attribute__((ext_vector_type(2))) float f32x2;
typedef __attribute__((ext_vector_type(2))) unsigned int u32x2;
typedef __attribute__((ext_vector_type(4))) unsigned int u32x4;

#if __has_builtin(__builtin_amdgcn_exp2f)
#define EXP2(x) __builtin_amdgcn_exp2f(x)
#else
#define EXP2(x) exp2f(x)
#endif

__device__ __forceinline__ half2v pk2(float a, float b) {
  return __builtin_bit_cast(half2v, __builtin_amdgcn_cvt_pkrtz(a, b));
}
__device__ __forceinline__ unsigned pk2u(float a, float b) {
  return __builtin_bit_cast(unsigned, __builtin_amdgcn_cvt_pkrtz(a, b));
}
__device__ __forceinline__ unsigned pkrn(float a, float b) {
  half2v r;
  r[0] = (_Float16)a;
  r[1] = (_Float16)b;
  return __builtin_bit_cast(unsigned, r);
}
__device__ __forceinline__ half8 cvt8rn(float4 a, float4 b) {
  half8 r;
  r[0] = (_Float16)a.x; r[1] = (_Float16)a.y;
  r[2] = (_Float16)a.z; r[3] = (_Float16)a.w;
  r[4] = (_Float16)b.x; r[5] = (_Float16)b.y;
  r[6] = (_Float16)b.z; r[7] = (_Float16)b.w;
  return r;
}
// c += pair.lo + pair.hi in one VALU op (v_dot2_f32_f16 with B=(1,1)).
__device__ __forceinline__ float fdot2acc(unsigned a, float c) {
#if __has_builtin(__builtin_amdgcn_fdot2)
  fp16x2 one = {(__fp16)1.0f, (__fp16)1.0f};
  return __builtin_amdgcn_fdot2(__builtin_bit_cast(fp16x2, a), one, c, false);
#else
  half2v v = __builtin_bit_cast(half2v, a);
  return c + (float)v[0] + (float)v[1];
#endif
}

// Quadrant swap between lane halves (verified end-to-end in R9/R11).
__device__ __forceinline__ void swap32(unsigned a, unsigned b, unsigned& r0,
                                       unsigned& r1, int lane) {
#if __has_builtin(__builtin_amdgcn_permlane32_swap)
  typedef __attribute__((ext_vector_type(2))) unsigned uint2v;
  uint2v s = __builtin_amdgcn_permlane32_swap(a, b, false, false);
  r0 = s[0];
  r1 = s[1];
#else
  unsigned ax = __shfl_xor((int)a, 32), bx = __shfl_xor((int)b, 32);
  const bool lo = lane < 32;
  r0 = lo ? a : bx;
  r1 = lo ? ax : b;
#endif
}

// ---------------------------------------------------------------------------
// Fused QKV GEMM (R16-proven, unchanged): x fp32 staged to LDS fp16 (packed
// pair writes), qkv_w fp32 converted RTN in-register, single-term fp16 MFMA.
// Q -> Qp [bh][n][32]*QSCL, K -> Kp [bh][n][32], V -> Vp [bh][32][n].
// grid (64, 6, 2), block 256 (4 waves, each 32m x 64n).
// ---------------------------------------------------------------------------
__global__ __launch_bounds__(256) void gemm_qkv(
    const float* __restrict__ Wf, const float* __restrict__ x,
    const float* __restrict__ bias, _Float16* __restrict__ Qp,
    _Float16* __restrict__ Kp, _Float16* __restrict__ Vp) {
  __shared__ _Float16 XT[64][72];  // [n][ch-in-chunk], 144B rows (16B-align)
  const int b = blockIdx.z, n0 = blockIdx.x * 64, m0 = blockIdx.y * 128;
  const int tid = threadIdx.x, w = tid >> 6, lane = tid & 63;
  const int lq = lane & 15, g = lane >> 4;
  const int mw = m0 + w * 32;
  const int cp = tid >> 4, nn = (tid & 15) * 4;
  f32x4 acc[2][4] = {};
  const size_t wr0 = (size_t)(mw + lq) * 256 + 8 * g;
  const size_t wr1 = (size_t)(mw + 16 + lq) * 256 + 8 * g;

  for (int kc = 0; kc < 4; ++kc) {
    if (kc) __syncthreads();
    #pragma unroll
    for (int i = 0; i < 2; ++i) {
      const int cb = (cp + 16 * i) * 2;  // even channel within chunk, 0..62
      const float* xs = x + ((size_t)(b * 256 + kc * 64 + cb)) * NSEQ + n0 + nn;
      float4 va = *(const float4*)(xs);
      float4 vb = *(const float4*)(xs + NSEQ);
      *(unsigned*)&XT[nn + 0][cb] = pkrn(va.x, vb.x);
      *(unsigned*)&XT[nn + 1][cb] = pkrn(va.y, vb.y);
      *(unsigned*)&XT[nn + 2][cb] = pkrn(va.z, vb.z);
      *(unsigned*)&XT[nn + 3][cb] = pkrn(va.w, vb.w);
    }
    __syncthreads();
    #pragma unroll
    for (int kh = 0; kh < 2; ++kh) {
      const int k0 = kc * 64 + kh * 32;
      float4 wa0 = *(const float4*)(Wf + wr0 + k0);
      float4 wa1 = *(const float4*)(Wf + wr0 + k0 + 4);
      float4 wb0 = *(const float4*)(Wf + wr1 + k0);
      float4 wb1 = *(const float4*)(Wf + wr1 + k0 + 4);
      half8 ah0 = cvt8rn(wa0, wa1);
      half8 ah1 = cvt8rn(wb0, wb1);
      const int dk = kh * 32 + 8 * g;
      #pragma unroll
      for (int ns = 0; ns < 4; ++ns) {
        half8 bh_ = *(const half8*)&XT[ns * 16 + lq][dk];
        acc[0][ns] = __builtin_amdgcn_mfma_f32_16x16x32_f16(ah0, bh_, acc[0][ns], 0, 0, 0);
        acc[1][ns] = __builtin_amdgcn_mfma_f32_16x16x32_f16(ah1, bh_, acc[1][ns], 0, 0, 0);
      }
    }
  }
  const int seg = mw >> 8;  // 0=Q, 1=K, 2=V
  const int hh = (mw >> 5) & 7;
  const int bhi = b * 8 + hh;
  #pragma unroll
  for (int ms = 0; ms < 2; ++ms) {
    const int dbase = ms * 16 + 4 * g;
    float4 bi = *(const float4*)(bias + mw + dbase);
    #pragma unroll
    for (int ns = 0; ns < 4; ++ns) {
      const int n = n0 + ns * 16 + lq;
      float v0 = acc[ms][ns][0] + bi.x;
      float v1 = acc[ms][ns][1] + bi.y;
      float v2 = acc[ms][ns][2] + bi.z;
      float v3 = acc[ms][ns][3] + bi.w;
      if (seg == 0) {
        v0 *= QSCL; v1 *= QSCL; v2 *= QSCL; v3 *= QSCL;
        u32x2 H;
        H[0] = pk2u(v0, v1);
        H[1] = pk2u(v2, v3);
        *(u32x2*)(Qp + ((size_t)bhi * NSEQ + n) * 32 + dbase) = H;
      } else if (seg == 1) {
        u32x2 H;
        H[0] = pk2u(v0, v1);
        H[1] = pk2u(v2, v3);
        *(u32x2*)(Kp + ((size_t)bhi * NSEQ + n) * 32 + dbase) = H;
      } else {
        Vp[((size_t)bhi * 32 + dbase + 0) * NSEQ + n] = (_Float16)v0;
        Vp[((size_t)bhi * 32 + dbase + 1) * NSEQ + n] = (_Float16)v1;
        Vp[((size_t)bhi * 32 + dbase + 2) * NSEQ + n] = (_Float16)v2;
        Vp[((size_t)bhi * 32 + dbase + 3) * NSEQ + n] = (_Float16)v3;
      }
    }
  }
}

// ---------------------------------------------------------------------------
// Flash attention partial: R19 body with PHASE-SPLIT compute (T15-style):
// per stream, BOTH kt-groups' QK MFMAs issue back-to-back before any
// softmax (sc0/sc1 live together, +32 VGPR), so PV(kt0) overlaps
// softmax(kt1) and the next stream's QK can overlap this stream's tail.
// setprio(1) narrowed to the softmax+PV cluster.
// grid (32, 8, 2): bx = qt(16) | ks(2)<<4. block 256 (4 waves).
// pp[(bh*2+ks)][q][32] normalized fp16 partial; lsum[bh][q][2] f32.
// ---------------------------------------------------------------------------
__global__ __launch_bounds__(256, 2) void attn_part(
    const _Float16* __restrict__ Qp, const _Float16* __restrict__ Kp,
    const _Float16* __restrict__ Vp, _Float16* __restrict__ pp,
    float* __restrict__ lsum) {
  const int b = blockIdx.z, h = blockIdx.y, bh = b * 8 + h;
  const int qt = blockIdx.x & 15, ks_ = blockIdx.x >> 4;
  const int tid = threadIdx.x, w = tid >> 6, lane = tid & 63;
  const int l31 = lane & 31, hw = lane >> 5;
  const int hi8 = hw * 8;
  const int n0 = qt * 256 + w * 64;  // wave's q base: 2 streams of 32

  half8 qf[2][2];
  #pragma unroll
  for (int s = 0; s < 2; ++s)
    #pragma unroll
    for (int dh = 0; dh < 2; ++dh)
      qf[s][dh] = *(const half8*)(Qp + ((size_t)bh * NSEQ + n0 + s * 32 + l31) * 32 +
                                  dh * 16 + hi8);

  f32x16 acc[2] = {};
  float lp[2][4] = {};
  const _Float16* Kb = Kp + ((size_t)bh * NSEQ + ks_ * 2048) * 32;
  const _Float16* Vb = Vp + (size_t)bh * 32 * NSEQ + ks_ * 2048;

  half8 kA[4], kB[4];

  auto kload = [&](half8* dst, int t) {
    const int key0 = t * 64;
    #pragma unroll
    for (int kt = 0; kt < 2; ++kt)
      #pragma unroll
      for (int dh = 0; dh < 2; ++dh)
        dst[kt * 2 + dh] = *(const half8*)(Kb + (size_t)(key0 + kt * 32 + l31) * 32 +
                                           dh * 16 + hi8);
  };

  auto compute = [&](const half8* kf, int t) {
    const int key0 = t * 64;
    half8 vf[4];
    #pragma unroll
    for (int c = 0; c < 4; ++c)
      vf[c] = *(const half8*)(Vb + (size_t)l31 * NSEQ + key0 + c * 16 + hi8);
    #pragma unroll
    for (int s = 0; s < 2; ++s) {
      // ---- QK phase: all 4 MFMAs for this stream, back-to-back ----
      f32x16 sc0 = {0.f, 0.f, 0.f, 0.f, 0.f, 0.f, 0.f, 0.f,
                    0.f, 0.f, 0.f, 0.f, 0.f, 0.f, 0.f, 0.f};
      f32x16 sc1 = sc0;
      sc0 = __builtin_amdgcn_mfma_f32_32x32x16_f16(kf[0], qf[s][0], sc0, 0, 0, 0);
      sc1 = __builtin_amdgcn_mfma_f32_32x32x16_f16(kf[2], qf[s][0], sc1, 0, 0, 0);
      sc0 = __builtin_amdgcn_mfma_f32_32x32x16_f16(kf[1], qf[s][1], sc0, 0, 0, 0);
      sc1 = __builtin_amdgcn_mfma_f32_32x32x16_f16(kf[3], qf[s][1], sc1, 0, 0, 0);
      // ---- softmax + PV per kt; PV(kt0) overlaps softmax(kt1) ----
      __builtin_amdgcn_s_setprio(1);
      #pragma unroll
      for (int kt = 0; kt < 2; ++kt) {
        const f32x16 sc = kt ? sc1 : sc0;
        float p[16];
        #pragma unroll
        for (int i = 0; i < 16; ++i) p[i] = EXP2(sc[i]);
        #pragma unroll
        for (int cc = 0; cc < 2; ++cc) {
          unsigned A01 = pk2u(p[cc * 8 + 0], p[cc * 8 + 1]);
          unsigned A23 = pk2u(p[cc * 8 + 2], p[cc * 8 + 3]);
          unsigned A45 = pk2u(p[cc * 8 + 4], p[cc * 8 + 5]);
          unsigned A67 = pk2u(p[cc * 8 + 6], p[cc * 8 + 7]);
          lp[s][0] = fdot2acc(A01, lp[s][0]);
          lp[s][1] = fdot2acc(A23, lp[s][1]);
          lp[s][2] = fdot2acc(A45, lp[s][2]);
          lp[s][3] = fdot2acc(A67, lp[s][3]);
          unsigned r0, r1, r2, r3;
          swap32(A01, A45, r0, r1, lane);
          swap32(A23, A67, r2, r3, lane);
          u32x4 W;
          W[0] = r0;
          W[1] = r2;
          W[2] = r1;
          W[3] = r3;
          half8 pb = __builtin_bit_cast(half8, W);
          acc[s] = __builtin_amdgcn_mfma_f32_32x32x16_f16(vf[kt * 2 + cc], pb, acc[s], 0, 0, 0);
        }
      }
      __builtin_amdgcn_s_setprio(0);
    }
  };

  kload(kA, 0);
  #pragma unroll 1
  for (int t = 0; t < 32; t += 2) {
    kload(kB, t + 1);
    compute(kA, t);
    kload(kA, t + 2 < 32 ? t + 2 : 31);
    compute(kB, t + 1);
  }

  // ---- per-stream l reduction; normalized fp16 partial + l ----
  #pragma unroll
  for (int s = 0; s < 2; ++s) {
    float l = (lp[s][0] + lp[s][1]) + (lp[s][2] + lp[s][3]);
    l += __shfl_xor(l, 32);
    const float inv = 1.f / l;
    const int q = n0 + s * 32 + l31;
    const size_t pbase = ((size_t)(bh * 2 + ks_) * NSEQ + q) * 32;
    #pragma unroll
    for (int rg = 0; rg < 4; ++rg) {
      const int d0 = rg * 8 + 4 * hw;
      float v0 = acc[s][rg * 4 + 0] * inv, v1 = acc[s][rg * 4 + 1] * inv;
      float v2 = acc[s][rg * 4 + 2] * inv, v3 = acc[s][rg * 4 + 3] * inv;
      u32x2 H;
      H[0] = pk2u(v0, v1);
      H[1] = pk2u(v2, v3);
      *(u32x2*)(pp + pbase + d0) = H;
    }
    if (lane < 32) lsum[((size_t)bh * NSEQ + q) * 2 + ks_] = l;
  }
}

// ---------------------------------------------------------------------------
// Output projection (R16-proven, unchanged): out_w fp32 split hi/lo
// in-register (2-term MFMA) + INLINE key-split combine in packed fp16.
// grid (64, 4, 2), block 256.
// ---------------------------------------------------------------------------
__global__ __launch_bounds__(256) void gemm_proj(
    const float* __restrict__ Wf, const _Float16* __restrict__ pp,
    const float* __restrict__ lsum, const float* __restrict__ bias,
    float* __restrict__ out) {
  const int b = blockIdx.z, n0 = blockIdx.x * 64, m0 = blockIdx.y * 64;
  const int tid = threadIdx.x, w = tid >> 6, lane = tid & 63;
  const int lq = lane & 15, g = lane >> 4;
  const int mw = m0 + w * 16;
  f32x4 acc[4] = {};
  const size_t wr = (size_t)(mw + lq) * 256 + 8 * g;
  #pragma unroll
  for (int k0 = 0; k0 < 256; k0 += 32) {
    float4 wa0 = *(const float4*)(Wf + wr + k0);
    float4 wa1 = *(const float4*)(Wf + wr + k0 + 4);
    half2v h0 = pk2(wa0.x, wa0.y), h1 = pk2(wa0.z, wa0.w);
    half2v h2 = pk2(wa1.x, wa1.y), h3 = pk2(wa1.z, wa1.w);
    half8 ah, al;
    ah[0] = h0[0]; ah[1] = h0[1]; ah[2] = h1[0]; ah[3] = h1[1];
    ah[4] = h2[0]; ah[5] = h2[1]; ah[6] = h3[0]; ah[7] = h3[1];
    half2v e0 = pk2(wa0.x - (float)h0[0], wa0.y - (float)h0[1]);
    half2v e1 = pk2(wa0.z - (float)h1[0], wa0.w - (float)h1[1]);
    half2v e2 = pk2(wa1.x - (float)h2[0], wa1.y - (float)h2[1]);
    half2v e3 = pk2(wa1.z - (float)h3[0], wa1.w - (float)h3[1]);
    al[0] = e0[0]; al[1] = e0[1]; al[2] = e1[0]; al[3] = e1[1];
    al[4] = e2[0]; al[5] = e2[1]; al[6] = e3[0]; al[7] = e3[1];
    const int c = k0 + 8 * g;  // channel of this 8-elem chunk
    const int hch = c >> 5, d0 = c & 31;
    const int bh = b * 8 + hch;
    #pragma unroll
    for (int ns = 0; ns < 4; ++ns) {
      const int n = n0 + ns * 16 + lq;
      const size_t pb = ((size_t)(bh * 2) * NSEQ + n) * 32 + d0;
      half8 pa = *(const half8*)(pp + pb);
      half8 pbp = *(const half8*)(pp + pb + (size_t)NSEQ * 32);
      f32x2 lv = *(const f32x2*)(lsum + ((size_t)bh * NSEQ + n) * 2);
      const float iv = 1.f / (lv[0] + lv[1]);
      const _Float16 w0h = (_Float16)(lv[0] * iv);
      const _Float16 w1h = (_Float16)(lv[1] * iv);
      half8 bh_ = pa * w0h + pbp * w1h;  // packed fp16 mul/fma
      acc[ns] = __builtin_amdgcn_mfma_f32_16x16x32_f16(ah, bh_, acc[ns], 0, 0, 0);
      acc[ns] = __builtin_amdgcn_mfma_f32_16x16x32_f16(al, bh_, acc[ns], 0, 0, 0);
    }
  }
  float4 bi = *(const float4*)(bias + mw + 4 * g);
  #pragma unroll
  for (int ns = 0; ns < 4; ++ns) {
    const int n = n0 + ns * 16 + lq;
    out[((size_t)b * 256 + mw + 4 * g + 0) * NSEQ + n] = acc[ns][0] + bi.x;
    out[((size_t)b * 256 + mw + 4 * g + 1) * NSEQ + n] = acc[ns][1] + bi.y;
    out[((size_t)b * 256 + mw + 4 * g + 2) * NSEQ + n] = acc[ns][2] + bi.z;
    out[((size_t)b * 256 + mw + 4 * g + 3) * NSEQ + n] = acc[ns][3] + bi.w;
  }
}

// ---------------------------------------------------------------------------
extern "C" void kernel_launch(void* const* d_in, const int* in_sizes, int n_in,
                              void* d_out, int out_size, void* d_ws, size_t ws_size,
                              hipStream_t stream) {
  const float* x = (const float*)d_in[0];
  const float* qkv_w = (const float*)d_in[1];
  const float* qkv_b = (const float*)d_in[2];
  const float* out_w = (const float*)d_in[3];
  const float* out_b = (const float*)d_in[4];
  float* out = (float*)d_out;

  char* ws = (char*)d_ws;
  _Float16* Vp = (_Float16*)(ws);                // [16][32][4096] 4MB
  _Float16* Qp = (_Float16*)(ws + (4u << 20));   // [16][4096][32] 4MB
  _Float16* Kp = (_Float16*)(ws + (8u << 20));   // 4MB
  _Float16* pp = (_Float16*)(ws + (12u << 20));  // [32 planes] 8MB
  float* lsum = (float*)(ws + (20u << 20));      // [16][4096][2] f32 512KB

  gemm_qkv<<<dim3(NSEQ / 64, 6, 2), 256, 0, stream>>>(qkv_w, x, qkv_b,
                                                      Qp, Kp, Vp);
  attn_part<<<dim3(32, 8, 2), 256, 0, stream>>>(Qp, Kp, Vp, pp, lsum);
  gemm_proj<<<dim3(NSEQ / 64, 4, 2), 256, 0, stream>>>(out_w, pp, lsum,
                                                       out_b, out);
}